// Round 16
// baseline (766.087 us; speedup 1.0000x reference)
//
// Round 16: R15 + intra-wave DEQ/MFMA interleave. Tile split into kh-phases; DEQ of the
// other half placed piecewise BETWEEN MFMA clusters (VALU fills matrix-pipe shadow);
// setprio removed (scheduler fence). Data plan unchanged: reg-B transposed packed q,
// A-only dbuf LDS 32KB, 128x256 tile, 4 waves, 2 blocks/CU, XCD n-fastest, NT stores.
#include <hip/hip_runtime.h>
#include <stdint.h>

#define TOKENS 8192
#define KDIM   4096
#define NDIM   11008
#define BM 128
#define BN 256
#define BK 64
#define KTILES (KDIM / BK)          // 64
#define PQ_BYTES (45088768u/8u*4u)  // 22544384
#define XH_BYTES (33554432ull*2ull) // 67108864
#define WS_PACKED ((size_t)PQ_BYTES + XH_BYTES)

typedef _Float16 f16x8 __attribute__((ext_vector_type(8)));
typedef _Float16 f16x2 __attribute__((ext_vector_type(2)));
typedef float    f32x4 __attribute__((ext_vector_type(4)));

typedef const __attribute__((address_space(1))) unsigned int* gptr_t;
typedef __attribute__((address_space(3))) unsigned int* lptr_t;

// ---- pass 1a: TRANSPOSED permuted pack. dword(column n, k-octet o) stored at
// (n>>4)*8192 + o*16 + (n&15). Nibble order [k0,k2,k4,k6,k1,k3,k5,k7] so
// ((d>>4p)&0x000F000F)|0x64006400 = fp16 pair (1024+k_{2p}, 1024+k_{2p+1}).
__global__ __launch_bounds__(256) void pack_qt(const int* __restrict__ q,
                                               unsigned int* __restrict__ pqt) {
    const unsigned int g = blockIdx.x * 256 + threadIdx.x;   // 0..5636095
    const int c  = g & 15;
    const int o  = (g >> 4) & 511;
    const int np = g >> 13;
    const int n  = np * 16 + c;
    const int4* p = (const int4*)(q + (size_t)n * KDIM + o * 8);
    const int4 a = p[0], b = p[1];
    unsigned int w = (unsigned int)(a.x & 15)
                   | ((unsigned int)(a.z & 15) << 4)
                   | ((unsigned int)(b.x & 15) << 8)
                   | ((unsigned int)(b.z & 15) << 12)
                   | ((unsigned int)(a.y & 15) << 16)
                   | ((unsigned int)(a.w & 15) << 20)
                   | ((unsigned int)(b.y & 15) << 24)
                   | ((unsigned int)(b.w & 15) << 28);
    pqt[g] = w;
}

// ---- pass 1b: x fp32 -> fp16 (exact) ----
__global__ __launch_bounds__(256) void cvt_x(const float* __restrict__ x,
                                             _Float16* __restrict__ xh) {
    const size_t idx = (size_t)(blockIdx.x * 256 + threadIdx.x) * 8;
    const float4* p = (const float4*)(x + idx);
    const float4 a = p[0], b = p[1];
    f16x8 o;
    o[0] = (_Float16)a.x; o[1] = (_Float16)a.y; o[2] = (_Float16)a.z; o[3] = (_Float16)a.w;
    o[4] = (_Float16)b.x; o[5] = (_Float16)b.y; o[6] = (_Float16)b.z; o[7] = (_Float16)b.w;
    *(f16x8*)(xh + idx) = o;
}

// ---- pass 2: 128x256 4-wave GEMM, A in dbuf LDS, reg-B, kh-phase interleave ----
__global__ __launch_bounds__(256, 2)
void wq_gemm_il(const _Float16* __restrict__ Xh, const unsigned int* __restrict__ Pqt,
                const float* __restrict__ Sc, const float* __restrict__ Zp,
                const float* __restrict__ Bi, float* __restrict__ Out)
{
    __shared__ __align__(16) _Float16 As[2][BM * BK];   // 2 x 16 KB

    const int t    = threadIdx.x;
    const int lane = t & 63;
    const int wid  = t >> 6;        // 0..3
    const int wnc  = wid;           // wave owns cols wnc*64..+64; all share 128 m-rows

    // XCD-bijective, n-fastest (2752 = 8*344)
    const unsigned int bid = blockIdx.x;
    const unsigned int wg  = (bid & 7u) * 344u + (bid >> 3);
    const int m0 = (int)(wg / 43u) * BM;
    const int n0 = (int)(wg % 43u) * BN;

    // A staging (proven conflict-free): gload_lds, linear LDS dest, pre-XOR'd source:
    // phys blk = logical ^ (row&7). Issue i covers rows i*32 + wid*8 + (lane>>3).
    const int alr = lane >> 3;
    const int alb = lane & 7;
    const _Float16* aSrc = Xh + (size_t)(m0 + wid * 8 + alr) * KDIM + ((alb ^ alr) << 3);

    // fragment read map
    const int fr = lane & 15;
    const int fq = lane >> 4;       // 0..3
    const int fx = fr & 7;

    // B per-lane sources (coalesced: wave covers 64 consecutive dwords per (j,kh)):
    // dword addr = (n0+wnc*64)*512 + j*8192 + kt*128 + kh*64 + fq*16 + fr
    const unsigned int* qbase = Pqt + (size_t)(n0 + wnc * 64) * 512 + fq * 16 + fr;
    const float* scol = Sc + n0 + wnc * 64 + fr;   // + g*NDIM + j*16
    const float* zcol = Zp + n0 + wnc * 64 + fr;

    f32x4 acc[8][4];
#pragma unroll
    for (int i = 0; i < 8; ++i)
#pragma unroll
        for (int j = 0; j < 4; ++j)
            acc[i][j] = f32x4{0.f, 0.f, 0.f, 0.f};

    const f16x2 k1024 = {(_Float16)1024.0f, (_Float16)1024.0f};

#define A_STAGE(buf, ktv) do {                                                        \
    _Pragma("unroll")                                                                 \
    for (int i_ = 0; i_ < 4; ++i_)                                                    \
        __builtin_amdgcn_global_load_lds(                                             \
            (gptr_t)(const void*)(aSrc + (size_t)i_ * 32 * KDIM + (ktv) * BK),        \
            (lptr_t)(void*)(&As[buf][i_ * 2048 + wid * 512]), 16, 0, 0);              \
} while (0)

#define DEQ_REG(dst, dw, s2v, z2v) do {                                               \
    unsigned int o_[4];                                                               \
    _Pragma("unroll")                                                                 \
    for (int p_ = 0; p_ < 4; ++p_) {                                                  \
        unsigned int u_ = (((dw) >> (4 * p_)) & 0x000F000Fu) | 0x64006400u;           \
        f16x2 h_ = __builtin_bit_cast(f16x2, u_);                                     \
        f16x2 q_ = h_ - k1024;                                                        \
        f16x2 w_ = q_ * (s2v) + (z2v);                                                \
        o_[p_] = __builtin_bit_cast(unsigned int, w_);                                \
    }                                                                                 \
    (dst) = __builtin_bit_cast(f16x8, uint4{o_[0], o_[1], o_[2], o_[3]});             \
} while (0)

// one MFMA cluster: m-pair p, k-half KH, operands from bfv
#define CLUSTER(p_, KH, bfv) do {                                                     \
    f16x8 af0_, af1_;                                                                 \
    af0_ = *(const f16x8*)&As[cur][(((p_) * 2 + 0) * 16 + fr) * 64 +                  \
                                   ((((KH) << 2) | fq) ^ fx) * 8];                    \
    af1_ = *(const f16x8*)&As[cur][(((p_) * 2 + 1) * 16 + fr) * 64 +                  \
                                   ((((KH) << 2) | fq) ^ fx) * 8];                    \
    _Pragma("unroll")                                                                 \
    for (int j_ = 0; j_ < 4; ++j_) {                                                  \
        acc[(p_) * 2 + 0][j_] = __builtin_amdgcn_mfma_f32_16x16x32_f16(               \
            af0_, bfv[j_], acc[(p_) * 2 + 0][j_], 0, 0, 0);                           \
        acc[(p_) * 2 + 1][j_] = __builtin_amdgcn_mfma_f32_16x16x32_f16(               \
            af1_, bfv[j_], acc[(p_) * 2 + 1][j_], 0, 0, 0);                           \
    }                                                                                 \
} while (0)

    unsigned int qc[8], qf[8];
    f16x8 bf0[4], bf1[4];
    f16x2 s2c[4], z2c[4], s2n[4], z2n[4];

    // ---- prologue: A(0) DMA; q(0) + s/z(group 0) ----
    A_STAGE(0, 0);
#pragma unroll
    for (int j = 0; j < 4; ++j)
#pragma unroll
        for (int kh = 0; kh < 2; ++kh)
            qc[j * 2 + kh] = qbase[j * 8192 + kh * 64];
#pragma unroll
    for (int j = 0; j < 4; ++j) {
        const float s_ = scol[j * 16];
        const float z_ = zcol[j * 16];
        s2c[j] = f16x2{(_Float16)s_, (_Float16)s_};
        z2c[j] = f16x2{(_Float16)z_, (_Float16)z_};
        s2n[j] = s2c[j]; z2n[j] = z2c[j];
    }
#pragma unroll
    for (int i = 0; i < 8; ++i) qf[i] = qc[i];
    __syncthreads();                      // A(0) + qc landed
    // dequant kh0 of tile 0
#pragma unroll
    for (int j = 0; j < 4; ++j) DEQ_REG(bf0[j], qc[j * 2 + 0], s2c[j], z2c[j]);

    int cur = 0;
    for (int kt = 0; kt < KTILES; ++kt) {
        const bool more = (kt + 1 < KTILES);

        // issue all next-tile loads up front (drained by this tile's end barrier)
        if (more) {
            A_STAGE(cur ^ 1, kt + 1);
#pragma unroll
            for (int j = 0; j < 4; ++j)
#pragma unroll
                for (int kh = 0; kh < 2; ++kh)
                    qf[j * 2 + kh] = qbase[j * 8192 + (kt + 1) * 128 + kh * 64];
            const int gn = (kt + 1) >> 1;
#pragma unroll
            for (int j = 0; j < 4; ++j) {
                const float s_ = scol[(size_t)gn * NDIM + j * 16];
                const float z_ = zcol[(size_t)gn * NDIM + j * 16];
                s2n[j] = f16x2{(_Float16)s_, (_Float16)s_};
                z2n[j] = f16x2{(_Float16)z_, (_Float16)z_};
            }
        }

        // ---- phase A: kh=0 MFMAs (bf0), DEQ bf1 (kh=1, this tile) between clusters
        CLUSTER(0, 0, bf0);
        DEQ_REG(bf1[0], qc[1], s2c[0], z2c[0]);
        CLUSTER(1, 0, bf0);
        DEQ_REG(bf1[1], qc[3], s2c[1], z2c[1]);
        CLUSTER(2, 0, bf0);
        DEQ_REG(bf1[2], qc[5], s2c[2], z2c[2]);
        CLUSTER(3, 0, bf0);
        DEQ_REG(bf1[3], qc[7], s2c[3], z2c[3]);

        // ---- phase B: kh=1 MFMAs (bf1), DEQ bf0 (kh=0, NEXT tile, from qf) between
        CLUSTER(0, 1, bf1);
        if (more) DEQ_REG(bf0[0], qf[0], s2n[0], z2n[0]);
        CLUSTER(1, 1, bf1);
        if (more) DEQ_REG(bf0[1], qf[2], s2n[1], z2n[1]);
        CLUSTER(2, 1, bf1);
        if (more) DEQ_REG(bf0[2], qf[4], s2n[2], z2n[2]);
        CLUSTER(3, 1, bf1);
        if (more) DEQ_REG(bf0[3], qf[6], s2n[3], z2n[3]);

        __syncthreads();   // drains A-DMA(kt+1); reads of cur done
#pragma unroll
        for (int i = 0; i < 8; ++i) qc[i] = qf[i];
#pragma unroll
        for (int j = 0; j < 4; ++j) { s2c[j] = s2n[j]; z2c[j] = z2n[j]; }
        cur ^= 1;
    }
#undef A_STAGE
#undef DEQ_REG
#undef CLUSTER

    // epilogue: C/D map col=lane&15, row=(lane>>4)*4+reg; out = f32(f16(acc)+f16(bias))
#pragma unroll
    for (int j = 0; j < 4; ++j) {
        const int n = n0 + wnc * 64 + j * 16 + fr;
        const _Float16 bv = (_Float16)Bi[n];
#pragma unroll
        for (int im = 0; im < 8; ++im) {
            const int mbase = m0 + im * 16 + fq * 4;
#pragma unroll
            for (int r = 0; r < 4; ++r) {
                const _Float16 h = (_Float16)acc[im][j][r] + bv;
                __builtin_nontemporal_store((float)h, &Out[(size_t)(mbase + r) * NDIM + n]);
            }
        }
    }
}

// ---------------- fallback: round-5 direct kernel (no workspace) ----------------
__global__ __launch_bounds__(256, 2)
void wq_gemm_direct(const float* __restrict__ X,  const int* __restrict__ Qw,
                    const float* __restrict__ Sc, const float* __restrict__ Zp,
                    const float* __restrict__ Bi, float* __restrict__ Out)
{
    __shared__ __align__(16) _Float16 As[128 * 32];
    __shared__ __align__(16) _Float16 Bs[128 * 32];
    const int t = threadIdx.x, lane = t & 63, wid = t >> 6;
    const int wr = wid >> 1, wc = wid & 1;
    const int n0 = blockIdx.x * 128, m0 = blockIdx.y * 128;
    const int srow = t >> 1, shalf = (t & 1) << 4;
    const float* xsrc = X + (size_t)(m0 + srow) * KDIM + shalf;
    const int*   qsrc = Qw + (size_t)(n0 + srow) * KDIM + shalf;
    const float* scp = Sc + n0 + srow;
    const float* zpp = Zp + n0 + srow;
    _Float16* adst = As + srow * 32 + shalf;
    _Float16* bdst = Bs + srow * 32 + shalf;
    const int fr = lane & 15, fq = lane >> 4;
    const _Float16* ard = As + (wr * 64 + fr) * 32 + fq * 8;
    const _Float16* brd = Bs + (wc * 64 + fr) * 32 + fq * 8;
    f32x4 acc[4][4];
#pragma unroll
    for (int i = 0; i < 4; ++i)
#pragma unroll
        for (int j = 0; j < 4; ++j) acc[i][j] = f32x4{0.f, 0.f, 0.f, 0.f};
    for (int kt = 0; kt < KDIM / 32; ++kt) {
        const int k0 = kt * 32;
        const float4* xp = (const float4*)(xsrc + k0);
        const float4 x0 = xp[0], x1 = xp[1], x2 = xp[2], x3 = xp[3];
        const float xv[16] = {x0.x, x0.y, x0.z, x0.w, x1.x, x1.y, x1.z, x1.w,
                              x2.x, x2.y, x2.z, x2.w, x3.x, x3.y, x3.z, x3.w};
        f16x8 a0, a1;
#pragma unroll
        for (int j = 0; j < 8; ++j) { a0[j] = (_Float16)xv[j]; a1[j] = (_Float16)xv[j + 8]; }
        const int g = k0 >> 7;
        const float sf = scp[(size_t)g * NDIM];
        const float zf = zpp[(size_t)g * NDIM];
        const int4* qp = (const int4*)(qsrc + k0);
        const int4 q0 = qp[0], q1 = qp[1], q2 = qp[2], q3 = qp[3];
        const int qv[16] = {q0.x, q0.y, q0.z, q0.w, q1.x, q1.y, q1.z, q1.w,
                            q2.x, q2.y, q2.z, q2.w, q3.x, q3.y, q3.z, q3.w};
        f16x8 w0, w1;
#pragma unroll
        for (int j = 0; j < 8; ++j) {
            w0[j] = (_Float16)((float)qv[j]     * sf + zf);
            w1[j] = (_Float16)((float)qv[j + 8] * sf + zf);
        }
        *(f16x8*)adst = a0; *(f16x8*)(adst + 8) = a1;
        *(f16x8*)bdst = w0; *(f16x8*)(bdst + 8) = w1;
        __syncthreads();
        f16x8 a[4], b[4];
#pragma unroll
        for (int i = 0; i < 4; ++i) a[i] = *(const f16x8*)(ard + i * 16 * 32);
#pragma unroll
        for (int j = 0; j < 4; ++j) b[j] = *(const f16x8*)(brd + j * 16 * 32);
#pragma unroll
        for (int i = 0; i < 4; ++i)
#pragma unroll
            for (int j = 0; j < 4; ++j)
                acc[i][j] = __builtin_amdgcn_mfma_f32_16x16x32_f16(a[i], b[j], acc[i][j], 0, 0, 0);
        __syncthreads();
    }
#pragma unroll
    for (int j = 0; j < 4; ++j) {
        const int n = n0 + wc * 64 + j * 16 + fr;
        const _Float16 bv = (_Float16)Bi[n];
#pragma unroll
        for (int i = 0; i < 4; ++i) {
            const int mbase = m0 + wr * 64 + i * 16 + fq * 4;
#pragma unroll
            for (int r = 0; r < 4; ++r) {
                const _Float16 h = (_Float16)acc[i][j][r] + bv;
                Out[(size_t)(mbase + r) * NDIM + n] = (float)h;
            }
        }
    }
}

extern "C" void kernel_launch(void* const* d_in, const int* in_sizes, int n_in,
                              void* d_out, int out_size, void* d_ws, size_t ws_size,
                              hipStream_t stream) {
    const float* x  = nullptr;
    const int*   q  = nullptr;
    const float* sc = nullptr;
    const float* zp = nullptr;
    const float* bi = nullptr;
    for (int i = 0; i < n_in; ++i) {
        switch (in_sizes[i]) {
            case 33554432: x = (const float*)d_in[i]; break;
            case 45088768: q = (const int*)d_in[i]; break;
            case 352256:   if (!sc) sc = (const float*)d_in[i];
                           else     zp = (const float*)d_in[i];
                           break;
            case 11008:    bi = (const float*)d_in[i]; break;
            default: break;
        }
    }
    if (!x || !q || !sc || !zp || !bi) {
        x  = (const float*)d_in[0];
        q  = (const int*)d_in[1];
        sc = (const float*)d_in[2];
        zp = (const float*)d_in[3];
        bi = (const float*)d_in[4];
    }
    float* out = (float*)d_out;

    if (ws_size >= WS_PACKED) {
        unsigned int* pqt = (unsigned int*)d_ws;
        _Float16*     xh  = (_Float16*)((char*)d_ws + PQ_BYTES);
        pack_qt<<<5636096 / 256, 256, 0, stream>>>(q, pqt);
        cvt_x<<<33554432 / 8 / 256, 256, 0, stream>>>(x, xh);
        wq_gemm_il<<<(TOKENS / BM) * (NDIM / BN), 256, 0, stream>>>(xh, pqt, sc, zp, bi, out);
    } else {
        dim3 grid(NDIM / 128, TOKENS / 128);
        wq_gemm_direct<<<grid, dim3(256), 0, stream>>>(x, q, sc, zp, bi, out);
    }
}